// Round 7
// baseline (3672.072 us; speedup 1.0000x reference)
//
#include <hip/hip_runtime.h>

typedef _Float16 half8 __attribute__((ext_vector_type(8)));
typedef float f32x4 __attribute__((ext_vector_type(4)));

#define TT 512
#define HH 512

// ws layout (bytes):
//   [0,        16777216)  x16   : [32 b][512 t][512 d] f16
//   [16777216, 50331648)  h_pk  : [2 dir][512 step][64 j][32 b][8 u] f16
//   [50331648, 50335744)  flags : [2 dir][8 slot][64 wg] int (epoch ring)
//   [50339840, 54534144)  Upk   : packed U frags f16 (2^21)
//   [54534144, 58728448)  Wpk   : packed W frags f16 (2^21)
#define OFF_HPK   16777216
#define OFF_FLAGS 50331648
#define OFF_UPK   50339840
#define OFF_WPK   54534144

struct BiasPtrs { const float* b[8]; };

struct PackParams {
  const float* U[8];
  const float* W[8];
  _Float16* Upk;
  _Float16* Wpk;
};

__global__ void convert_x_kernel(const float* __restrict__ x, _Float16* __restrict__ x16) {
  const size_t i = ((size_t)blockIdx.x * blockDim.x + threadIdx.x) * 8;
  float4 v0 = *(const float4*)(x + i);
  float4 v1 = *(const float4*)(x + i + 4);
  half8 h;
  h[0] = (_Float16)v0.x; h[1] = (_Float16)v0.y; h[2] = (_Float16)v0.z; h[3] = (_Float16)v0.w;
  h[4] = (_Float16)v1.x; h[5] = (_Float16)v1.y; h[6] = (_Float16)v1.z; h[7] = (_Float16)v1.w;
  *(half8*)(x16 + i) = h;
}

// Pack U/W into MFMA B-fragment order:
// idx = ((((d*64 + j)*2 + ct)*16 + kt)*64 + l)*8 + jj
// lane l: r15=l&15, kg=l>>4; col -> g=r15&3, u=j*8+ct*4+(r15>>2); k=kt*32+kg*8+jj.
__global__ void pack_frags_kernel(PackParams p) {
  const unsigned n = blockIdx.x * 256 + threadIdx.x;   // 2 * 2^21 total
  const unsigned o = n & 2097151u;
  const int sel = n >> 21;                              // 0 = U, 1 = W
  const int jj = o & 7, l = (o >> 3) & 63, kt = (o >> 9) & 15;
  const int ct = (o >> 13) & 1, j = (o >> 14) & 63, d = (o >> 20) & 1;
  const int r15 = l & 15, kg = l >> 4;
  const int g = r15 & 3;
  const int u = j * 8 + ct * 4 + (r15 >> 2);
  const int k = kt * 32 + kg * 8 + jj;
  const float* M = sel ? p.W[4 * d + g] : p.U[4 * d + g];
  _Float16* dst = sel ? p.Wpk : p.Upk;
  dst[o] = (_Float16)M[k * HH + u];
}

__global__ void zero_kernel(int* __restrict__ p) {
  p[(size_t)blockIdx.x * blockDim.x + threadIdx.x] = 0;
}

__device__ __forceinline__ float hsig(float x) {
  return fminf(fmaxf(fmaf(x, 0.2f, 0.5f), 0.0f), 1.0f);
}

// 128 WGs x 512 thr (cooperative). WG = (d = bid>>6, j = bid&63) owns units
// [j*8, j*8+8) x 4 gates = 32 cols.
// WAVE SPECIALIZATION: waves 0-3 (role 0, "critical") compute h(s-1)@U and
// hold ONLY the U fragments; waves 4-7 (role 1, "helper") compute x_t@W in
// the SAME barrier window and hold ONLY the W fragments (same register array,
// disjoint live paths). Elementwise: pre = zlds(hU) + xwlds(xW) + bias.
// Sync: round-3-proven parallel epoch flags + 64-lane coalesced poll.
__global__ __launch_bounds__(512, 1) void lstm_scan_kernel(
    const _Float16* __restrict__ x16,
    _Float16* __restrict__ h_pk,
    int* __restrict__ flags,
    const _Float16* __restrict__ Upk,
    const _Float16* __restrict__ Wpk,
    BiasPtrs bp) {
  const int tid  = threadIdx.x;       // 0..511
  const int bid  = blockIdx.x;        // 0..127
  const int d    = bid >> 6;
  const int j    = bid & 63;
  const int w    = tid >> 6;          // 0..7
  const int l    = tid & 63;
  const int role = w >> 2;            // 0 = critical (h@U), 1 = helper (x@W)
  const int wl   = w & 3;
  const int rt   = wl & 1;
  const int ct   = wl >> 1;
  const int r15  = l & 15;
  const int kg   = l >> 4;
  const int arow = rt * 16 + r15;

  // One fragment array per thread; U for critical waves, W for helpers.
  half8 frag[16];
  {
    const half8* src = (const half8*)(role ? Wpk : Upk);
    const int base = (((d * 64 + j) * 2 + ct) * 16) * 64 + l;
#pragma unroll
    for (int kt = 0; kt < 16; ++kt) frag[kt] = src[base + kt * 64];
  }

  // Elementwise identity (threads 0..255 only).
  const int b_e  = (tid & 255) >> 3;
  const int uu_e = tid & 7;
  const int u_e  = j * 8 + uu_e;
  const int slot_e = (uu_e >> 2) * 16 + (uu_e & 3) * 4;
  f32x4 biasv;
#pragma unroll
  for (int g = 0; g < 4; ++g) biasv[g] = bp.b[4 * d + g][u_e];

  __shared__ __align__(16) float zlds[32 * 36];      // hU
  __shared__ __align__(16) float xwlds[32 * 36];     // xW
  __shared__ __align__(16) unsigned short hlds[256];

  float c = 0.0f;

  for (int s = 0; s < TT; ++s) {
    const int t = d ? (TT - 1 - s) : s;

    // Critical wave 0 polls: all 64 producer flags of this direction (one
    // coalesced 64-lane load per round).
    if (role == 0 && s > 0 && tid < 64) {
      const int* fl = flags + ((d * 8 + ((s - 1) & 7)) << 6) + tid;
      while (__hip_atomic_load(fl, __ATOMIC_RELAXED, __HIP_MEMORY_SCOPE_AGENT) < s) {
        __builtin_amdgcn_s_sleep(1);
      }
    }
    __syncthreads();   // B1: h(s-1) published & visible

    if (role == 0) {
      // h(s-1) @ U
      f32x4 acc0 = {0,0,0,0}, acc1 = {0,0,0,0}, acc2 = {0,0,0,0}, acc3 = {0,0,0,0};
      if (s > 0) {
        const half8* hb = (const half8*)(h_pk + ((size_t)(d * TT + (s - 1))) * 16384);
#pragma unroll
        for (int kt = 0; kt < 16; ++kt) {
          half8 a = hb[(kt * 4 + kg) * 32 + arow];
          if ((kt & 3) == 0)      acc0 = __builtin_amdgcn_mfma_f32_16x16x32_f16(a, frag[kt], acc0, 0, 0, 0);
          else if ((kt & 3) == 1) acc1 = __builtin_amdgcn_mfma_f32_16x16x32_f16(a, frag[kt], acc1, 0, 0, 0);
          else if ((kt & 3) == 2) acc2 = __builtin_amdgcn_mfma_f32_16x16x32_f16(a, frag[kt], acc2, 0, 0, 0);
          else                    acc3 = __builtin_amdgcn_mfma_f32_16x16x32_f16(a, frag[kt], acc3, 0, 0, 0);
        }
      }
      const f32x4 z = (acc0 + acc1) + (acc2 + acc3);
#pragma unroll
      for (int i = 0; i < 4; ++i)
        zlds[(rt * 16 + kg * 4 + i) * 36 + ct * 16 + r15] = z[i];
    } else {
      // x_t @ W (same step, parallel with h@U on the other waves)
      f32x4 acc0 = {0,0,0,0}, acc1 = {0,0,0,0}, acc2 = {0,0,0,0}, acc3 = {0,0,0,0};
      const half8* xb = (const half8*)(x16 + ((size_t)arow * TT + t) * HH);
#pragma unroll
      for (int kt = 0; kt < 16; ++kt) {
        half8 a = xb[kt * 4 + kg];
        if ((kt & 3) == 0)      acc0 = __builtin_amdgcn_mfma_f32_16x16x32_f16(a, frag[kt], acc0, 0, 0, 0);
        else if ((kt & 3) == 1) acc1 = __builtin_amdgcn_mfma_f32_16x16x32_f16(a, frag[kt], acc1, 0, 0, 0);
        else if ((kt & 3) == 2) acc2 = __builtin_amdgcn_mfma_f32_16x16x32_f16(a, frag[kt], acc2, 0, 0, 0);
        else                    acc3 = __builtin_amdgcn_mfma_f32_16x16x32_f16(a, frag[kt], acc3, 0, 0, 0);
      }
      const f32x4 z = (acc0 + acc1) + (acc2 + acc3);
#pragma unroll
      for (int i = 0; i < 4; ++i)
        xwlds[(rt * 16 + kg * 4 + i) * 36 + ct * 16 + r15] = z[i];
    }
    __syncthreads();   // B2: zlds + xwlds complete

    // Elementwise LSTM cell (threads 0..255).
    if (tid < 256) {
      f32x4 pre = *(const f32x4*)&zlds[(size_t)b_e * 36 + slot_e]
                + *(const f32x4*)&xwlds[(size_t)b_e * 36 + slot_e]
                + biasv;
      const float ig = hsig(pre[0]);
      const float fg = hsig(pre[1]);
      const float gg = tanhf(pre[2]);
      const float og = hsig(pre[3]);
      c = fg * c + ig * gg;
      const float h = og * tanhf(c);
      hlds[tid] = __builtin_bit_cast(unsigned short, (_Float16)h);
    }
    __syncthreads();   // B3: hlds ready

    // Publish: wave 0 stores the WG's contiguous 512 B slice, drains exactly
    // those stores, then lane 0 sets this WG's epoch flag (parallel, no RMW).
    if (tid < 64) {
      const unsigned long long v = ((const unsigned long long*)hlds)[tid];
      unsigned long long* dst = (unsigned long long*)h_pk +
                                ((size_t)(d * TT + s) * 64 + j) * 64 + tid;
      __hip_atomic_store(dst, v, __ATOMIC_RELAXED, __HIP_MEMORY_SCOPE_AGENT);
      asm volatile("s_waitcnt vmcnt(0)" ::: "memory");
      if (tid == 0)
        __hip_atomic_store(flags + ((d * 8 + (s & 7)) << 6) + j, s + 1,
                           __ATOMIC_RELAXED, __HIP_MEMORY_SCOPE_AGENT);
    }
  }
}

// out[b][t][u] = h_fwd[t] + h_bwd[t]  (Theano: backward stacked in iteration
// order without re-reversing; scan stored bwd iteration s at slot s).
__global__ void sum_out_kernel(const _Float16* __restrict__ h_pk, float* __restrict__ out) {
  const unsigned idx = blockIdx.x * 256 + threadIdx.x;   // 32*512*64
  const int j = idx & 63;
  const int t = (idx >> 6) & 511;
  const int b = idx >> 15;
  half8 hf = ((const half8*)h_pk)[((size_t)t * 64 + j) * 32 + b];
  half8 hg = ((const half8*)h_pk)[((size_t)(TT + t) * 64 + j) * 32 + b];
  float* o = out + (((size_t)b * TT + t) * HH + j * 8);
  float4 r0, r1;
  r0.x = (float)hf[0] + (float)hg[0]; r0.y = (float)hf[1] + (float)hg[1];
  r0.z = (float)hf[2] + (float)hg[2]; r0.w = (float)hf[3] + (float)hg[3];
  r1.x = (float)hf[4] + (float)hg[4]; r1.y = (float)hf[5] + (float)hg[5];
  r1.z = (float)hf[6] + (float)hg[6]; r1.w = (float)hf[7] + (float)hg[7];
  *(float4*)o = r0;
  *(float4*)(o + 4) = r1;
}

extern "C" void kernel_launch(void* const* d_in, const int* in_sizes, int n_in,
                              void* d_out, int out_size, void* d_ws, size_t ws_size,
                              hipStream_t stream) {
  (void)in_sizes; (void)n_in; (void)out_size; (void)ws_size;
  char* ws = (char*)d_ws;
  _Float16* x16   = (_Float16*)ws;
  _Float16* h_pk  = (_Float16*)(ws + OFF_HPK);
  int*      flags = (int*)(ws + OFF_FLAGS);
  _Float16* Upk   = (_Float16*)(ws + OFF_UPK);
  _Float16* Wpk   = (_Float16*)(ws + OFF_WPK);

  convert_x_kernel<<<4096, 256, 0, stream>>>((const float*)d_in[0], x16);

  PackParams pp;
  for (int g = 0; g < 8; ++g) {
    pp.W[g] = (const float*)d_in[1 + g];
    pp.U[g] = (const float*)d_in[9 + g];
  }
  pp.Upk = Upk; pp.Wpk = Wpk;
  pack_frags_kernel<<<16384, 256, 0, stream>>>(pp);

  zero_kernel<<<4, 256, 0, stream>>>(flags);   // 1024 ints = epoch flag ring

  BiasPtrs bp;
  for (int g = 0; g < 8; ++g) bp.b[g] = (const float*)d_in[17 + g];

  void* args[] = { (void*)&x16, (void*)&h_pk, (void*)&flags,
                   (void*)&Upk, (void*)&Wpk, (void*)&bp };
  hipLaunchCooperativeKernel((const void*)lstm_scan_kernel, dim3(128), dim3(512),
                             args, 0, stream);

  sum_out_kernel<<<4096, 256, 0, stream>>>(h_pk, (float*)d_out);
}

// Round 8
// 2839.569 us; speedup vs baseline: 1.2932x; 1.2932x over previous
//
#include <hip/hip_runtime.h>

typedef _Float16 half8 __attribute__((ext_vector_type(8)));
typedef float f32x4 __attribute__((ext_vector_type(4)));

#define TT 512
#define HH 512

// ws layout (bytes):
//   [0,        16777216)  x16   : [32 b][512 t][512 d] f16
//   [16777216, 50331648)  h_pk  : [2 dir][512 step][64 j][32 b][8 u] f16
//   [50331648, 50335744)  flags : [2 dir][8 slot][64 wg] int (epoch ring)
//   [50339840, 54534144)  Upk   : packed U frags f16 (2^21)
//   [54534144, 58728448)  Wpk   : packed W frags f16 (2^21)
#define OFF_HPK   16777216
#define OFF_FLAGS 50331648
#define OFF_UPK   50339840
#define OFF_WPK   54534144

struct BiasPtrs { const float* b[8]; };

struct PackParams {
  const float* U[8];
  const float* W[8];
  _Float16* Upk;
  _Float16* Wpk;
};

// Launder: opaque no-op asm — later uses must consume the asm OUTPUT register,
// so the compiler can no longer rematerialize the originating load per step.
#define KEEP8(A) asm volatile("" \
  : "+v"((A)[0]), "+v"((A)[1]), "+v"((A)[2]), "+v"((A)[3]), \
    "+v"((A)[4]), "+v"((A)[5]), "+v"((A)[6]), "+v"((A)[7]))

__global__ void convert_x_kernel(const float* __restrict__ x, _Float16* __restrict__ x16) {
  const size_t i = ((size_t)blockIdx.x * blockDim.x + threadIdx.x) * 8;
  float4 v0 = *(const float4*)(x + i);
  float4 v1 = *(const float4*)(x + i + 4);
  half8 h;
  h[0] = (_Float16)v0.x; h[1] = (_Float16)v0.y; h[2] = (_Float16)v0.z; h[3] = (_Float16)v0.w;
  h[4] = (_Float16)v1.x; h[5] = (_Float16)v1.y; h[6] = (_Float16)v1.z; h[7] = (_Float16)v1.w;
  *(half8*)(x16 + i) = h;
}

// Pack U/W into MFMA B-fragment order:
// idx = ((((d*64 + j)*2 + ct)*16 + kt)*64 + l)*8 + jj
// lane l: r15=l&15, kg=l>>4; col -> g=r15&3, u=j*8+ct*4+(r15>>2); k=kt*32+kg*8+jj.
__global__ void pack_frags_kernel(PackParams p) {
  const unsigned n = blockIdx.x * 256 + threadIdx.x;   // 2 * 2^21 total
  const unsigned o = n & 2097151u;
  const int sel = n >> 21;                              // 0 = U, 1 = W
  const int jj = o & 7, l = (o >> 3) & 63, kt = (o >> 9) & 15;
  const int ct = (o >> 13) & 1, j = (o >> 14) & 63, d = (o >> 20) & 1;
  const int r15 = l & 15, kg = l >> 4;
  const int g = r15 & 3;
  const int u = j * 8 + ct * 4 + (r15 >> 2);
  const int k = kt * 32 + kg * 8 + jj;
  const float* M = sel ? p.W[4 * d + g] : p.U[4 * d + g];
  _Float16* dst = sel ? p.Wpk : p.Upk;
  dst[o] = (_Float16)M[k * HH + u];
}

__global__ void zero_kernel(int* __restrict__ p) {
  p[(size_t)blockIdx.x * blockDim.x + threadIdx.x] = 0;
}

__device__ __forceinline__ float hsig(float x) {
  return fminf(fmaxf(fmaf(x, 0.2f, 0.5f), 0.0f), 1.0f);
}

// tanh(x) = 1 - 2/(exp(2x)+1): v_exp_f32 + v_rcp_f32, ~2 ulp — replaces the
// multi-branch libm tanhf on the critical path.
__device__ __forceinline__ float fast_tanh(float x) {
  const float e = __expf(2.0f * x);
  return fmaf(-2.0f, __builtin_amdgcn_rcpf(e + 1.0f), 1.0f);
}

// 128 WGs x 256 thr (cooperative). WG = (d = bid>>6, j = bid&63) owns units
// [j*8, j*8+8) x 4 gates = 32 cols. Wave w: rows rt=(w&1)*16, cols ct=(w>>1)*16,
// full K=512. U/W fragments are register-resident (laundered via KEEP8).
// Sync: parallel per-WG epoch flags (ring of 8), 64-lane coalesced poll.
__global__ __launch_bounds__(256, 1) void lstm_scan_kernel(
    const _Float16* __restrict__ x16,
    _Float16* __restrict__ h_pk,
    int* __restrict__ flags,
    const _Float16* __restrict__ Upk,
    const _Float16* __restrict__ Wpk,
    BiasPtrs bp) {
  const int tid = threadIdx.x;
  const int bid = blockIdx.x;
  const int d   = bid >> 6;
  const int j   = bid & 63;
  const int w   = tid >> 6;
  const int l   = tid & 63;
  const int r15 = l & 15;
  const int kg  = l >> 4;
  const int rt  = w & 1;
  const int ct  = w >> 1;

  half8 uf[16], wf[16];
  {
    const half8* ub = (const half8*)Upk;
    const half8* wb = (const half8*)Wpk;
    const int base = (((d * 64 + j) * 2 + ct) * 16) * 64 + l;
#pragma unroll
    for (int kt = 0; kt < 16; ++kt) {
      uf[kt] = ub[base + kt * 64];
      wf[kt] = wb[base + kt * 64];
    }
  }
  // Pin all 32 fragments (128 VGPRs) in registers for the whole scan.
  KEEP8(uf); KEEP8(uf + 8); KEEP8(wf); KEEP8(wf + 8);

  const int b_e  = tid >> 3;
  const int uu_e = tid & 7;
  const int u_e  = j * 8 + uu_e;
  const int slot_e = (uu_e >> 2) * 16 + (uu_e & 3) * 4;
  f32x4 biasv;
#pragma unroll
  for (int g = 0; g < 4; ++g) biasv[g] = bp.b[4 * d + g][u_e];
  asm volatile("" : "+v"(biasv));   // pin bias too

  __shared__ __align__(16) float zlds[32 * 36];
  __shared__ __align__(16) unsigned short hlds[256];

  const int arow = rt * 16 + r15;
  float c = 0.0f;

  for (int s = 0; s < TT; ++s) {
    const int t = d ? (TT - 1 - s) : s;

    f32x4 acc0 = {0,0,0,0}, acc1 = {0,0,0,0}, acc2 = {0,0,0,0}, acc3 = {0,0,0,0};

    // x_t @ W — independent of the sync; overlaps the flag wait.
    {
      const half8* xb = (const half8*)(x16 + ((size_t)arow * TT + t) * HH);
#pragma unroll
      for (int kt = 0; kt < 16; ++kt) {
        half8 a = xb[kt * 4 + kg];
        if ((kt & 3) == 0)      acc0 = __builtin_amdgcn_mfma_f32_16x16x32_f16(a, wf[kt], acc0, 0, 0, 0);
        else if ((kt & 3) == 1) acc1 = __builtin_amdgcn_mfma_f32_16x16x32_f16(a, wf[kt], acc1, 0, 0, 0);
        else if ((kt & 3) == 2) acc2 = __builtin_amdgcn_mfma_f32_16x16x32_f16(a, wf[kt], acc2, 0, 0, 0);
        else                    acc3 = __builtin_amdgcn_mfma_f32_16x16x32_f16(a, wf[kt], acc3, 0, 0, 0);
      }
    }
    __builtin_amdgcn_sched_barrier(0);

    if (s > 0) {
      // All 64 producer flags of this direction: one coalesced 64-lane load
      // per poll round.
      if (tid < 64) {
        const int* fl = flags + ((d * 8 + ((s - 1) & 7)) << 6) + tid;
        while (__hip_atomic_load(fl, __ATOMIC_RELAXED, __HIP_MEMORY_SCOPE_AGENT) < s) {
          __builtin_amdgcn_s_sleep(1);
        }
      }
      __syncthreads();

      // h(s-1) @ U — 16 independent cached loads (1 round trip), U from VGPRs.
      const half8* hb = (const half8*)(h_pk + ((size_t)(d * TT + (s - 1))) * 16384);
#pragma unroll
      for (int kt = 0; kt < 16; ++kt) {
        half8 a = hb[(kt * 4 + kg) * 32 + arow];
        if ((kt & 3) == 0)      acc0 = __builtin_amdgcn_mfma_f32_16x16x32_f16(a, uf[kt], acc0, 0, 0, 0);
        else if ((kt & 3) == 1) acc1 = __builtin_amdgcn_mfma_f32_16x16x32_f16(a, uf[kt], acc1, 0, 0, 0);
        else if ((kt & 3) == 2) acc2 = __builtin_amdgcn_mfma_f32_16x16x32_f16(a, uf[kt], acc2, 0, 0, 0);
        else                    acc3 = __builtin_amdgcn_mfma_f32_16x16x32_f16(a, uf[kt], acc3, 0, 0, 0);
      }
    }
    const f32x4 z = (acc0 + acc1) + (acc2 + acc3);

    // z -> LDS. D-frag: col = r15, row = kg*4 + i.
#pragma unroll
    for (int i = 0; i < 4; ++i)
      zlds[(rt * 16 + kg * 4 + i) * 36 + ct * 16 + r15] = z[i];
    __syncthreads();

    // Elementwise LSTM cell.
    f32x4 pre = *(const f32x4*)&zlds[(size_t)b_e * 36 + slot_e] + biasv;
    const float ig = hsig(pre[0]);
    const float fg = hsig(pre[1]);
    const float gg = fast_tanh(pre[2]);
    const float og = hsig(pre[3]);
    c = fg * c + ig * gg;
    const float h = og * fast_tanh(c);

    hlds[tid] = __builtin_bit_cast(unsigned short, (_Float16)h);
    __syncthreads();

    // Publish: wave 0 stores the WG's contiguous 512 B slice, drains exactly
    // those stores, then lane 0 sets this WG's epoch flag (parallel, no RMW).
    if (tid < 64) {
      const unsigned long long v = ((const unsigned long long*)hlds)[tid];
      unsigned long long* dst = (unsigned long long*)h_pk +
                                ((size_t)(d * TT + s) * 64 + j) * 64 + tid;
      __hip_atomic_store(dst, v, __ATOMIC_RELAXED, __HIP_MEMORY_SCOPE_AGENT);
      asm volatile("s_waitcnt vmcnt(0)" ::: "memory");
      if (tid == 0)
        __hip_atomic_store(flags + ((d * 8 + (s & 7)) << 6) + j, s + 1,
                           __ATOMIC_RELAXED, __HIP_MEMORY_SCOPE_AGENT);
    }
  }
}

// out[b][t][u] = h_fwd[t] + h_bwd[t]  (Theano: backward stacked in iteration
// order without re-reversing; scan stored bwd iteration s at slot s).
__global__ void sum_out_kernel(const _Float16* __restrict__ h_pk, float* __restrict__ out) {
  const unsigned idx = blockIdx.x * 256 + threadIdx.x;   // 32*512*64
  const int j = idx & 63;
  const int t = (idx >> 6) & 511;
  const int b = idx >> 15;
  half8 hf = ((const half8*)h_pk)[((size_t)t * 64 + j) * 32 + b];
  half8 hg = ((const half8*)h_pk)[((size_t)(TT + t) * 64 + j) * 32 + b];
  float* o = out + (((size_t)b * TT + t) * HH + j * 8);
  float4 r0, r1;
  r0.x = (float)hf[0] + (float)hg[0]; r0.y = (float)hf[1] + (float)hg[1];
  r0.z = (float)hf[2] + (float)hg[2]; r0.w = (float)hf[3] + (float)hg[3];
  r1.x = (float)hf[4] + (float)hg[4]; r1.y = (float)hf[5] + (float)hg[5];
  r1.z = (float)hf[6] + (float)hg[6]; r1.w = (float)hf[7] + (float)hg[7];
  *(float4*)o = r0;
  *(float4*)(o + 4) = r1;
}

extern "C" void kernel_launch(void* const* d_in, const int* in_sizes, int n_in,
                              void* d_out, int out_size, void* d_ws, size_t ws_size,
                              hipStream_t stream) {
  (void)in_sizes; (void)n_in; (void)out_size; (void)ws_size;
  char* ws = (char*)d_ws;
  _Float16* x16   = (_Float16*)ws;
  _Float16* h_pk  = (_Float16*)(ws + OFF_HPK);
  int*      flags = (int*)(ws + OFF_FLAGS);
  _Float16* Upk   = (_Float16*)(ws + OFF_UPK);
  _Float16* Wpk   = (_Float16*)(ws + OFF_WPK);

  convert_x_kernel<<<4096, 256, 0, stream>>>((const float*)d_in[0], x16);

  PackParams pp;
  for (int g = 0; g < 8; ++g) {
    pp.W[g] = (const float*)d_in[1 + g];
    pp.U[g] = (const float*)d_in[9 + g];
  }
  pp.Upk = Upk; pp.Wpk = Wpk;
  pack_frags_kernel<<<16384, 256, 0, stream>>>(pp);

  zero_kernel<<<4, 256, 0, stream>>>(flags);   // 1024 ints = epoch flag ring

  BiasPtrs bp;
  for (int g = 0; g < 8; ++g) bp.b[g] = (const float*)d_in[17 + g];

  void* args[] = { (void*)&x16, (void*)&h_pk, (void*)&flags,
                   (void*)&Upk, (void*)&Wpk, (void*)&bp };
  hipLaunchCooperativeKernel((const void*)lstm_scan_kernel, dim3(128), dim3(256),
                             args, 0, stream);

  sum_out_kernel<<<4096, 256, 0, stream>>>(h_pk, (float*)d_out);
}